// Round 6
// baseline (756.475 us; speedup 1.0000x reference)
//
#include <hip/hip_runtime.h>
#include <math.h>

// M=2048, AVGF=16 (17 rows), HA=16 heads, DH=128, TK=4 blocks.
// GEMM out[i,l] = sum_m act'[i,m] * W[l,m].
// gemmL: block = 256 thr = 4 waves; wave owns 4 W rows (lane=16q+t: group q
// -> row, t -> k-slice). Act slab [NR][512] staged once to LDS with fused
// transform (LN / plane-sum+bias+gelu). 8 weight float4 loads issued up
// front; k-reduce = 4 shfl steps in 16-lane groups. k-split planes
// P[y][i][l]; consumers sum planes inline; redln updates ss + stats.

__global__ void k0_init(const float* __restrict__ x,
                        const float* __restrict__ bias,
                        const float* __restrict__ cls,
                        float* __restrict__ ss,
                        float* __restrict__ altx) {
    int idx = blockIdx.x * 256 + threadIdx.x;
    if (idx < 17 * 2048) {
        int r = idx >> 11, m = idx & 2047;
        float v = bias[idx];
        if (r == 0) v += cls[m];
        ss[idx] = v;
    }
    if (idx < 16 * 2048) {
        int i = idx >> 11, m = idx & 2047;
        int c1 = m >> 6, c2 = m & 63;
        const float* p = x + (size_t)(c2 * 32 + c1) * 160 + i * 10;
        float s = 0.f;
#pragma unroll
        for (int j = 0; j < 10; ++j) s += p[j];
        altx[idx] = s * 0.1f;
    }
}

// MODE 0: act'=act ; MODE 1: act'=LN(act) via st(mean,rstd),g,b ;
// MODE 2: act'=gelu(sum_{s<SP} act_planes + b)   (act=P planes, stride ANRL)
template <int NR, int MODE>
__global__ __launch_bounds__(256) void gemmL(
    const float* __restrict__ W, const float* __restrict__ act,
    const float* __restrict__ st, const float* __restrict__ g,
    const float* __restrict__ b, float* __restrict__ P,
    int L, int K, int SP, int ANRL) {
    __shared__ float abuf[NR][512];
    const int tid = threadIdx.x;
    const int lane = tid & 63;
    const int qg = lane >> 4;          // row group 0..3
    const int tl = lane & 15;          // k-lane in group
    const int wv = tid >> 6;
    const int l0 = blockIdx.x * 16 + wv * 4;
    const int k0 = blockIdx.y * 512;

    // ---- stage act' [NR][512] with fused transform ----
    for (int e = tid; e < NR * 128; e += 256) {
        const int i = e >> 7, c4 = e & 127;
        const int m = k0 + c4 * 4;
        float4 v4;
        if (MODE == 2) {
            v4 = *reinterpret_cast<const float4*>(act + (size_t)i * K + m);
            for (int s = 1; s < SP; ++s) {
                const float4 p4 = *reinterpret_cast<const float4*>(
                    act + (size_t)s * ANRL + (size_t)i * K + m);
                v4.x += p4.x; v4.y += p4.y; v4.z += p4.z; v4.w += p4.w;
            }
            const float4 b4 = *reinterpret_cast<const float4*>(b + m);
            v4.x += b4.x; v4.y += b4.y; v4.z += b4.z; v4.w += b4.w;
            v4.x = 0.5f * v4.x * (1.f + erff(v4.x * 0.70710678f));
            v4.y = 0.5f * v4.y * (1.f + erff(v4.y * 0.70710678f));
            v4.z = 0.5f * v4.z * (1.f + erff(v4.z * 0.70710678f));
            v4.w = 0.5f * v4.w * (1.f + erff(v4.w * 0.70710678f));
        } else {
            v4 = *reinterpret_cast<const float4*>(act + (size_t)i * K + m);
            if (MODE == 1) {
                const float mean = st[2 * i], rstd = st[2 * i + 1];
                const float4 g4 = *reinterpret_cast<const float4*>(g + m);
                const float4 b4 = *reinterpret_cast<const float4*>(b + m);
                v4.x = (v4.x - mean) * rstd * g4.x + b4.x;
                v4.y = (v4.y - mean) * rstd * g4.y + b4.y;
                v4.z = (v4.z - mean) * rstd * g4.z + b4.z;
                v4.w = (v4.w - mean) * rstd * g4.w + b4.w;
            }
        }
        *reinterpret_cast<float4*>(&abuf[i][c4 * 4]) = v4;
    }
    __syncthreads();

    // ---- all 8 weight float4 loads up front ----
    const float* Wrow = W + (size_t)(l0 + qg) * K + k0;
    float4 w[8];
#pragma unroll
    for (int c = 0; c < 2; ++c)
#pragma unroll
        for (int s = 0; s < 4; ++s)
            w[c * 4 + s] = *reinterpret_cast<const float4*>(
                Wrow + c * 256 + s * 64 + tl * 4);

    float acc[NR];
#pragma unroll
    for (int i = 0; i < NR; ++i) acc[i] = 0.f;

#pragma unroll
    for (int c = 0; c < 2; ++c)
#pragma unroll
        for (int s = 0; s < 4; ++s) {
            const int off = c * 256 + s * 64 + tl * 4;
            const float4 w4 = w[c * 4 + s];
#pragma unroll
            for (int i = 0; i < NR; ++i) {
                const float4 a4 = *reinterpret_cast<const float4*>(&abuf[i][off]);
                acc[i] += a4.x * w4.x + a4.y * w4.y + a4.z * w4.z + a4.w * w4.w;
            }
        }

    // ---- k-reduce within 16-lane group ----
#pragma unroll
    for (int i = 0; i < NR; ++i) {
#pragma unroll
        for (int off = 8; off; off >>= 1) acc[i] += __shfl_xor(acc[i], off);
    }
    // lane tl stores output row index i = tl (static select chain)
    float vout = acc[0];
#pragma unroll
    for (int i = 1; i < 16; ++i)
        if (i < NR && tl == i) vout = acc[i];
    const size_t pb = (size_t)blockIdx.y * NR * L + l0 + qg;
    if (tl < NR) P[pb + (size_t)tl * L] = vout;
    if (NR > 16 && tl == 0) P[pb + (size_t)16 * L] = acc[16];
}

// ss[row] += sum_S P[row] (+fb); write st(mean,rstd); optional final LN out
__global__ void redln(const float* __restrict__ P, int S, int rowoff, int NRL,
                      const float* __restrict__ fb, float* __restrict__ ss,
                      float* __restrict__ st, const float* __restrict__ g,
                      const float* __restrict__ b, float* __restrict__ lnout) {
    const int row = blockIdx.x;
    const int tid = threadIdx.x;
    const int base = row * 2048;
    float vv[8];
    float s = 0.f, q = 0.f;
#pragma unroll
    for (int c = 0; c < 8; ++c) {
        int col = tid + c * 256;
        float xv = ss[base + col];
        if (row >= rowoff) {
            const float* pp = P + (size_t)(row - rowoff) * 2048 + col;
            for (int y = 0; y < S; ++y) xv += pp[(size_t)y * NRL];
        }
        if (fb != nullptr) xv += fb[col];
        ss[base + col] = xv;
        vv[c] = xv;
        s += xv;
        q += xv * xv;
    }
#pragma unroll
    for (int off = 32; off; off >>= 1) {
        s += __shfl_xor(s, off);
        q += __shfl_xor(q, off);
    }
    __shared__ float red[8];
    int wvi = tid >> 6;
    if ((tid & 63) == 0) { red[wvi] = s; red[4 + wvi] = q; }
    __syncthreads();
    s = red[0] + red[1] + red[2] + red[3];
    q = red[4] + red[5] + red[6] + red[7];
    float mean = s * (1.f / 2048.f);
    float var = q * (1.f / 2048.f) - mean * mean;
    float rstd = rsqrtf(var + 1e-5f);
    if (tid == 0) { st[2 * row] = mean; st[2 * row + 1] = rstd; }
    if (lnout != nullptr) {
#pragma unroll
        for (int c = 0; c < 8; ++c) {
            int col = tid + c * 256;
            lnout[base + col] = (vv[c] - mean) * rstd * g[col] + b[col];
        }
    }
}

// one block per head; sums the 4 qkv planes inline
__global__ void attn_kernel(const float* __restrict__ Pq, float* __restrict__ imv) {
    int h = blockIdx.x, lane = threadIdx.x;
    const float scale = 0.08838834764831845f;  // 1/sqrt(128)
    float run0 = 0.f, run1 = 0.f;
    for (int i = 0; i < 17; ++i) {
        const size_t idx = (size_t)i * 6144 + h * 128;
        float q0 = 0.f, q1 = 0.f, k0 = 0.f, k1 = 0.f, v0 = 0.f, v1 = 0.f;
#pragma unroll
        for (int s = 0; s < 4; ++s) {
            const float* base = Pq + (size_t)s * 104448 + idx;
            q0 += base[lane];        q1 += base[lane + 64];
            k0 += base[2048 + lane]; k1 += base[2048 + lane + 64];
            v0 += base[4096 + lane]; v1 += base[4096 + lane + 64];
        }
        float p = q0 * k0 + q1 * k1;
#pragma unroll
        for (int off = 32; off; off >>= 1) p += __shfl_xor(p, off);
        float rsa = p * scale;
        float iv0 = rsa * v0, iv1 = rsa * v1;
        float o0, o1;
        if (i < 16) { run0 += iv0; run1 += iv1; o0 = run0; o1 = run1; }
        else        { o0 = iv0; o1 = iv1; }
        imv[(size_t)i * 2048 + h * 128 + lane] = o0;
        imv[(size_t)i * 2048 + h * 128 + lane + 64] = o1;
    }
}

extern "C" void kernel_launch(void* const* d_in, const int* in_sizes, int n_in,
                              void* d_out, int out_size, void* d_ws, size_t ws_size,
                              hipStream_t stream) {
    const float* x      = (const float*)d_in[0];
    const float* weight = (const float*)d_in[1];
    const float* bias   = (const float*)d_in[2];
    const float* cls    = (const float*)d_in[3];
    const float* Wqkv   = (const float*)d_in[4];
    const float* Wo     = (const float*)d_in[5];
    const float* ln1_g  = (const float*)d_in[6];
    const float* ln1_b  = (const float*)d_in[7];
    const float* ln2_g  = (const float*)d_in[8];
    const float* ln2_b  = (const float*)d_in[9];
    const float* ln3_g  = (const float*)d_in[10];
    const float* ln3_b  = (const float*)d_in[11];
    const float* fc1_w  = (const float*)d_in[12];
    const float* fc1_b  = (const float*)d_in[13];
    const float* fc2_w  = (const float*)d_in[14];
    const float* fc2_b  = (const float*)d_in[15];
    float* out = (float*)d_out;

    float* ws   = (float*)d_ws;
    float* ss   = ws;                  // 34816
    float* altx = ws + 34816;          // 32768
    float* imv  = ws + 67584;          // 34816
    float* st0  = ws + 102400;         // 34
    float* st1  = ws + 102464;         // 34
    float* Pa   = ws + 102528;         // 557056 (max: fc1 4x17x8192)
    float* Pb   = ws + 659584;         // 557056 (fc2 16x17x2048)

    k0_init<<<136, 256, 0, stream>>>(x, bias, cls, ss, altx);
    // ss[1:17] += altx @ weight.T   (4 planes [16][2048])
    gemmL<16, 0><<<dim3(128, 4), 256, 0, stream>>>(
        weight, altx, nullptr, nullptr, nullptr, Pa, 2048, 2048, 0, 0);
    redln<<<17, 256, 0, stream>>>(Pa, 4, 1, 32768, nullptr, ss, st0,
                                  nullptr, nullptr, nullptr);

    for (int k = 0; k < 4; ++k) {
        // qkv planes = Wqkv[k] @ ln1(ss)   (4 planes [17][6144])
        gemmL<17, 1><<<dim3(384, 4), 256, 0, stream>>>(
            Wqkv + (size_t)k * 12582912, ss, st0, ln1_g, ln1_b, Pa,
            6144, 2048, 0, 0);
        attn_kernel<<<16, 64, 0, stream>>>(Pa, imv);
        // Wo planes  (4 planes [17][2048])
        gemmL<17, 0><<<dim3(128, 4), 256, 0, stream>>>(
            Wo + (size_t)k * 4194304, imv, nullptr, nullptr, nullptr, Pa,
            2048, 2048, 0, 0);
        redln<<<17, 256, 0, stream>>>(Pa, 4, 0, 34816, nullptr, ss, st1,
                                      nullptr, nullptr, nullptr);
        // fc1 planes = fc1_w @ ln2(ss)  (4 planes [17][8192], raw)
        gemmL<17, 1><<<dim3(512, 4), 256, 0, stream>>>(
            fc1_w, ss, st1, ln2_g, ln2_b, Pa, 8192, 2048, 0, 0);
        // fc2 planes = fc2_w @ gelu(sum fc1 planes + fc1_b) (16 planes [17][2048])
        gemmL<17, 2><<<dim3(128, 16), 256, 0, stream>>>(
            fc2_w, Pa, nullptr, nullptr, fc1_b, Pb, 2048, 8192, 4, 139264);
        if (k < 3)
            redln<<<17, 256, 0, stream>>>(Pb, 16, 0, 34816, fc2_b, ss, st0,
                                          nullptr, nullptr, nullptr);
        else
            redln<<<17, 256, 0, stream>>>(Pb, 16, 0, 34816, fc2_b, ss, st0,
                                          ln3_g, ln3_b, out);
    }
}

// Round 7
// 686.286 us; speedup vs baseline: 1.1023x; 1.1023x over previous
//
#include <hip/hip_runtime.h>
#include <math.h>

// M=2048, AVGF=16 (17 rows), HA=16 heads, DH=128, TK=4 blocks.
// gemmT: out[i,l] = sum_m act[i,m] * W[l,m].
// block 256 thr = 4 waves; wave owns 4 consecutive W rows, streams them in
// 1KB-per-inst chunks (lane*4 cols). Acts double-buffered in LDS via
// global_load_lds (16B), one barrier per 256-col chunk, weight prefetch.
// k-split planes P[y][i][l]; consumers (attn/red_gelu/redln) sum planes.

__global__ void k0_init(const float* __restrict__ x,
                        const float* __restrict__ bias,
                        const float* __restrict__ cls,
                        float* __restrict__ ss,
                        float* __restrict__ altx) {
    int idx = blockIdx.x * 256 + threadIdx.x;
    if (idx < 17 * 2048) {
        int r = idx >> 11, m = idx & 2047;
        float v = bias[idx];
        if (r == 0) v += cls[m];
        ss[idx] = v;
    }
    if (idx < 16 * 2048) {
        int i = idx >> 11, m = idx & 2047;
        int c1 = m >> 6, c2 = m & 63;
        const float* p = x + (size_t)(c2 * 32 + c1) * 160 + i * 10;
        float s = 0.f;
#pragma unroll
        for (int j = 0; j < 10; ++j) s += p[j];
        altx[idx] = s * 0.1f;
    }
}

template <int NR>
__global__ __launch_bounds__(256, 4) void gemmT(
    const float* __restrict__ W, const float* __restrict__ act,
    float* __restrict__ P, int L, int K, int NC) {
    __shared__ float abuf[2][NR][256];
    const int tid = threadIdx.x;
    const int lane = tid & 63;
    const int wv = tid >> 6;
    const int l0 = blockIdx.x * 16 + wv * 4;
    const int k0 = blockIdx.y * (NC << 8);

    // stage chunk 0 into buf 0 (async global->LDS, 16B/lane)
    for (int i = wv; i < NR; i += 4)
        __builtin_amdgcn_global_load_lds(
            (const __attribute__((address_space(1))) unsigned int*)
                (act + (size_t)i * K + k0 + lane * 4),
            (__attribute__((address_space(3))) unsigned int*)(&abuf[0][i][0]),
            16, 0, 0);

    float acc[NR][4];
#pragma unroll
    for (int i = 0; i < NR; ++i)
#pragma unroll
        for (int r = 0; r < 4; ++r) acc[i][r] = 0.f;

    const float* Wbase = W + (size_t)l0 * K + k0;
    float4 wp[4], wn[4];
#pragma unroll
    for (int r = 0; r < 4; ++r)
        wp[r] = *reinterpret_cast<const float4*>(Wbase + (size_t)r * K + lane * 4);
#pragma unroll
    for (int r = 0; r < 4; ++r) wn[r] = wp[r];

    __syncthreads();  // stage(0) + wp ready

    for (int c = 0; c < NC; ++c) {
        if (c + 1 < NC) {
            // stage chunk c+1 into the other buffer
            for (int i = wv; i < NR; i += 4)
                __builtin_amdgcn_global_load_lds(
                    (const __attribute__((address_space(1))) unsigned int*)
                        (act + (size_t)i * K + k0 + (c + 1) * 256 + lane * 4),
                    (__attribute__((address_space(3))) unsigned int*)
                        (&abuf[(c + 1) & 1][i][0]),
                    16, 0, 0);
            // prefetch next weight chunk
#pragma unroll
            for (int r = 0; r < 4; ++r)
                wn[r] = *reinterpret_cast<const float4*>(
                    Wbase + (size_t)r * K + (c + 1) * 256 + lane * 4);
        }
        const float* ab = &abuf[c & 1][0][0];
#pragma unroll
        for (int i = 0; i < NR; ++i) {
            const float4 a4 = *reinterpret_cast<const float4*>(ab + i * 256 + lane * 4);
            acc[i][0] += a4.x * wp[0].x + a4.y * wp[0].y + a4.z * wp[0].z + a4.w * wp[0].w;
            acc[i][1] += a4.x * wp[1].x + a4.y * wp[1].y + a4.z * wp[1].z + a4.w * wp[1].w;
            acc[i][2] += a4.x * wp[2].x + a4.y * wp[2].y + a4.z * wp[2].z + a4.w * wp[2].w;
            acc[i][3] += a4.x * wp[3].x + a4.y * wp[3].y + a4.z * wp[3].z + a4.w * wp[3].w;
        }
        __syncthreads();
#pragma unroll
        for (int r = 0; r < 4; ++r) wp[r] = wn[r];
    }

    // in-wave butterfly k-reduce; one output per lane
    float vout = 0.f, vout2 = 0.f;
#pragma unroll
    for (int i = 0; i < NR; ++i)
#pragma unroll
        for (int r = 0; r < 4; ++r) {
            float v = acc[i][r];
#pragma unroll
            for (int off = 32; off; off >>= 1) v += __shfl_xor(v, off);
            if (i < 16) { if (lane == i * 4 + r) vout = v; }
            else        { if (lane == r)         vout2 = v; }
        }
    const size_t pb = (size_t)blockIdx.y * NR * L + l0;
    P[pb + (size_t)(lane >> 2) * L + (lane & 3)] = vout;
    if (NR > 16 && lane < 4) P[pb + (size_t)16 * L + lane] = vout2;
}

// tbuf = gelu(sum S planes + fc1_b)
__global__ void red_gelu(const float* __restrict__ P, const float* __restrict__ fb,
                         float* __restrict__ out, int S, int NRL) {
    int idx = blockIdx.x * 256 + threadIdx.x;
    float s = fb[idx & 8191];
    for (int y = 0; y < S; ++y) s += P[(size_t)y * NRL + idx];
    out[idx] = 0.5f * s * (1.f + erff(s * 0.70710678f));
}

// one block per row: ss[row] += sum_S P[row] (+fb); lnout = LN(ss)*g+b
__global__ void redln(const float* __restrict__ P, int S, int rowoff, int NRL,
                      const float* __restrict__ fb, float* __restrict__ ss,
                      const float* __restrict__ g, const float* __restrict__ b,
                      float* __restrict__ lnout) {
    const int row = blockIdx.x;
    const int tid = threadIdx.x;
    const int base = row * 2048;
    float vv[8];
    float s = 0.f, q = 0.f;
#pragma unroll
    for (int c = 0; c < 8; ++c) {
        int col = tid + c * 256;
        float xv = ss[base + col];
        if (row >= rowoff) {
            const float* pp = P + (size_t)(row - rowoff) * 2048 + col;
            for (int y = 0; y < S; ++y) xv += pp[(size_t)y * NRL];
        }
        if (fb != nullptr) xv += fb[col];
        ss[base + col] = xv;
        vv[c] = xv;
        s += xv;
        q += xv * xv;
    }
#pragma unroll
    for (int off = 32; off; off >>= 1) {
        s += __shfl_xor(s, off);
        q += __shfl_xor(q, off);
    }
    __shared__ float red[8];
    int wvi = tid >> 6;
    if ((tid & 63) == 0) { red[wvi] = s; red[4 + wvi] = q; }
    __syncthreads();
    s = red[0] + red[1] + red[2] + red[3];
    q = red[4] + red[5] + red[6] + red[7];
    float mean = s * (1.f / 2048.f);
    float var = q * (1.f / 2048.f) - mean * mean;
    float rstd = rsqrtf(var + 1e-5f);
#pragma unroll
    for (int c = 0; c < 8; ++c) {
        int col = tid + c * 256;
        lnout[base + col] = (vv[c] - mean) * rstd * g[col] + b[col];
    }
}

// one block per head; sums the 4 qkv k-planes inline
__global__ void attn_kernel(const float* __restrict__ Pq, float* __restrict__ imv) {
    int h = blockIdx.x, lane = threadIdx.x;
    const float scale = 0.08838834764831845f;  // 1/sqrt(128)
    float run0 = 0.f, run1 = 0.f;
    for (int i = 0; i < 17; ++i) {
        const size_t idx = (size_t)i * 6144 + h * 128;
        float q0 = 0.f, q1 = 0.f, k0 = 0.f, k1 = 0.f, v0 = 0.f, v1 = 0.f;
#pragma unroll
        for (int s = 0; s < 4; ++s) {
            const float* base = Pq + (size_t)s * 104448 + idx;
            q0 += base[lane];        q1 += base[lane + 64];
            k0 += base[2048 + lane]; k1 += base[2048 + lane + 64];
            v0 += base[4096 + lane]; v1 += base[4096 + lane + 64];
        }
        float p = q0 * k0 + q1 * k1;
#pragma unroll
        for (int off = 32; off; off >>= 1) p += __shfl_xor(p, off);
        float rsa = p * scale;
        float iv0 = rsa * v0, iv1 = rsa * v1;
        float o0, o1;
        if (i < 16) { run0 += iv0; run1 += iv1; o0 = run0; o1 = run1; }
        else        { o0 = iv0; o1 = iv1; }
        imv[(size_t)i * 2048 + h * 128 + lane] = o0;
        imv[(size_t)i * 2048 + h * 128 + lane + 64] = o1;
    }
}

extern "C" void kernel_launch(void* const* d_in, const int* in_sizes, int n_in,
                              void* d_out, int out_size, void* d_ws, size_t ws_size,
                              hipStream_t stream) {
    const float* x      = (const float*)d_in[0];
    const float* weight = (const float*)d_in[1];
    const float* bias   = (const float*)d_in[2];
    const float* cls    = (const float*)d_in[3];
    const float* Wqkv   = (const float*)d_in[4];
    const float* Wo     = (const float*)d_in[5];
    const float* ln1_g  = (const float*)d_in[6];
    const float* ln1_b  = (const float*)d_in[7];
    const float* ln2_g  = (const float*)d_in[8];
    const float* ln2_b  = (const float*)d_in[9];
    const float* ln3_g  = (const float*)d_in[10];
    const float* ln3_b  = (const float*)d_in[11];
    const float* fc1_w  = (const float*)d_in[12];
    const float* fc1_b  = (const float*)d_in[13];
    const float* fc2_w  = (const float*)d_in[14];
    const float* fc2_b  = (const float*)d_in[15];
    float* out = (float*)d_out;

    float* ws     = (float*)d_ws;
    float* ss     = ws;                  // 34816
    float* altx   = ws + 34816;          // 32768
    float* imv    = ws + 67584;          // 34816
    float* tbuf   = ws + 102400;         // 139264
    float* ln1buf = ws + 241664;         // 34816
    float* ln2buf = ws + 276480;         // 34816
    float* P      = ws + 311296;         // 417792 max (qkv 4 planes)

    k0_init<<<136, 256, 0, stream>>>(x, bias, cls, ss, altx);
    // ss[1:17] += altx @ weight.T  (4 planes [16][2048], slab 512)
    gemmT<16><<<dim3(128, 4), 256, 0, stream>>>(weight, altx, P, 2048, 2048, 2);
    redln<<<17, 256, 0, stream>>>(P, 4, 1, 32768, nullptr, ss, ln1_g, ln1_b, ln1buf);

    for (int k = 0; k < 4; ++k) {
        // qkv = Wqkv[k] @ ln1buf  (4 planes [17][6144], slab 512)
        gemmT<17><<<dim3(384, 4), 256, 0, stream>>>(
            Wqkv + (size_t)k * 12582912, ln1buf, P, 6144, 2048, 2);
        attn_kernel<<<16, 64, 0, stream>>>(P, imv);
        // ss += imv @ Wo[k].T  (4 planes [17][2048], slab 512)
        gemmT<17><<<dim3(128, 4), 256, 0, stream>>>(
            Wo + (size_t)k * 4194304, imv, P, 2048, 2048, 2);
        redln<<<17, 256, 0, stream>>>(P, 4, 0, 34816, nullptr, ss, ln2_g, ln2_b, ln2buf);
        // fc1 raw  (2 planes [17][8192], slab 1024)
        gemmT<17><<<dim3(512, 2), 256, 0, stream>>>(fc1_w, ln2buf, P, 8192, 2048, 4);
        red_gelu<<<544, 256, 0, stream>>>(P, fc1_b, tbuf, 2, 139264);
        // fc2  (8 planes [17][2048], slab 1024)
        gemmT<17><<<dim3(128, 8), 256, 0, stream>>>(fc2_w, tbuf, P, 2048, 8192, 4);
        if (k < 3)
            redln<<<17, 256, 0, stream>>>(P, 8, 0, 34816, fc2_b, ss, ln1_g, ln1_b, ln1buf);
        else
            redln<<<17, 256, 0, stream>>>(P, 8, 0, 34816, fc2_b, ss, ln3_g, ln3_b, out);
    }
}

// Round 8
// 684.292 us; speedup vs baseline: 1.1055x; 1.0029x over previous
//
#include <hip/hip_runtime.h>
#include <math.h>

// M=2048, AVGF=16 (17 rows), HA=16 heads, DH=128, TK=4 blocks.
// gemmP: out[i,l] = sum_m act[i,m] * W[l,m]. Block = 16 W rows x slab
// (NC 256-col chunks). W+act chunks stream through double-buffered LDS via
// global_load_lds; raw s_barrier + manual vmcnt so the next chunk's loads
// stay in flight during compute (no vmcnt(0)-before-barrier drain).
// k-split planes P[y][i][l]; consumers (attn/red_gelu/redln) sum planes.

__global__ void k0_init(const float* __restrict__ x,
                        const float* __restrict__ bias,
                        const float* __restrict__ cls,
                        float* __restrict__ ss,
                        float* __restrict__ altx) {
    int idx = blockIdx.x * 256 + threadIdx.x;
    if (idx < 17 * 2048) {
        int r = idx >> 11, m = idx & 2047;
        float v = bias[idx];
        if (r == 0) v += cls[m];
        ss[idx] = v;
    }
    if (idx < 16 * 2048) {
        int i = idx >> 11, m = idx & 2047;
        int c1 = m >> 6, c2 = m & 63;
        const float* p = x + (size_t)(c2 * 32 + c1) * 160 + i * 10;
        float s = 0.f;
#pragma unroll
        for (int j = 0; j < 10; ++j) s += p[j];
        altx[idx] = s * 0.1f;
    }
}

template <int NR, int NC>
__global__ __launch_bounds__(256, 2) void gemmP(
    const float* __restrict__ W, const float* __restrict__ act,
    float* __restrict__ P, int L, int K) {
    __shared__ float Wb[2][16][256];
    __shared__ float Ab[2][NR][256];
    const int tid = threadIdx.x;
    const int lane = tid & 63;
    const int wv = tid >> 6;
    const int l0 = blockIdx.x * 16;
    const int k0 = blockIdx.y * (NC * 256);

#define STAGE(c, buf)                                                         \
    do {                                                                      \
        const int koff_ = k0 + (c) * 256 + lane * 4;                          \
        for (int r_ = wv; r_ < 16; r_ += 4)                                   \
            __builtin_amdgcn_global_load_lds(                                 \
                (const __attribute__((address_space(1))) unsigned int*)       \
                    (W + (size_t)(l0 + r_) * K + koff_),                      \
                (__attribute__((address_space(3))) unsigned int*)             \
                    (&Wb[buf][r_][0]), 16, 0, 0);                             \
        for (int i_ = wv; i_ < NR; i_ += 4)                                   \
            __builtin_amdgcn_global_load_lds(                                 \
                (const __attribute__((address_space(1))) unsigned int*)       \
                    (act + (size_t)i_ * K + koff_),                           \
                (__attribute__((address_space(3))) unsigned int*)             \
                    (&Ab[buf][i_][0]), 16, 0, 0);                             \
    } while (0)

    STAGE(0, 0);

    float acc[NR][4];
#pragma unroll
    for (int i = 0; i < NR; ++i)
#pragma unroll
        for (int r = 0; r < 4; ++r) acc[i][r] = 0.f;

    for (int c = 0; c < NC; ++c) {
        // my stage(c) writes have landed (only outstanding group)
        asm volatile("s_waitcnt vmcnt(0)" ::: "memory");
        // everyone's stage(c) landed; everyone's compute(c-1) done
        __builtin_amdgcn_s_barrier();
        asm volatile("" ::: "memory");
        if (c + 1 < NC) STAGE(c + 1, (c + 1) & 1);
        asm volatile("" ::: "memory");
        // compute chunk c from LDS; stage(c+1) stays in flight
        const float* wb = &Wb[c & 1][wv * 4][0];
        const float* ab = &Ab[c & 1][0][0];
        float4 w4[4];
#pragma unroll
        for (int r = 0; r < 4; ++r)
            w4[r] = *reinterpret_cast<const float4*>(wb + r * 256 + lane * 4);
#pragma unroll
        for (int i = 0; i < NR; ++i) {
            const float4 a4 =
                *reinterpret_cast<const float4*>(ab + i * 256 + lane * 4);
            acc[i][0] += a4.x * w4[0].x + a4.y * w4[0].y + a4.z * w4[0].z + a4.w * w4[0].w;
            acc[i][1] += a4.x * w4[1].x + a4.y * w4[1].y + a4.z * w4[1].z + a4.w * w4[1].w;
            acc[i][2] += a4.x * w4[2].x + a4.y * w4[2].y + a4.z * w4[2].z + a4.w * w4[2].w;
            acc[i][3] += a4.x * w4[3].x + a4.y * w4[3].y + a4.z * w4[3].z + a4.w * w4[3].w;
        }
    }
#undef STAGE

    // in-wave butterfly k-reduce; one output per lane
    float vout = 0.f, vout2 = 0.f;
#pragma unroll
    for (int i = 0; i < NR; ++i)
#pragma unroll
        for (int r = 0; r < 4; ++r) {
            float v = acc[i][r];
#pragma unroll
            for (int off = 32; off; off >>= 1) v += __shfl_xor(v, off);
            if (i < 16) { if (lane == i * 4 + r) vout = v; }
            else        { if (lane == r)         vout2 = v; }
        }
    const size_t pb = (size_t)blockIdx.y * NR * L + l0 + wv * 4;
    P[pb + (size_t)(lane >> 2) * L + (lane & 3)] = vout;
    if (NR > 16 && lane < 4) P[pb + (size_t)16 * L + lane] = vout2;
}

// tbuf = gelu(sum S planes + fc1_b)
__global__ void red_gelu(const float* __restrict__ P, const float* __restrict__ fb,
                         float* __restrict__ out, int S, int NRL) {
    int idx = blockIdx.x * 256 + threadIdx.x;
    float s = fb[idx & 8191];
    for (int y = 0; y < S; ++y) s += P[(size_t)y * NRL + idx];
    out[idx] = 0.5f * s * (1.f + erff(s * 0.70710678f));
}

// one block per row: ss[row] += sum_S P[row] (+fb); lnout = LN(ss)*g+b
__global__ void redln(const float* __restrict__ P, int S, int rowoff, int NRL,
                      const float* __restrict__ fb, float* __restrict__ ss,
                      const float* __restrict__ g, const float* __restrict__ b,
                      float* __restrict__ lnout) {
    const int row = blockIdx.x;
    const int tid = threadIdx.x;
    const int base = row * 2048;
    float vv[8];
    float s = 0.f, q = 0.f;
#pragma unroll
    for (int c = 0; c < 8; ++c) {
        int col = tid + c * 256;
        float xv = ss[base + col];
        if (row >= rowoff) {
            const float* pp = P + (size_t)(row - rowoff) * 2048 + col;
            for (int y = 0; y < S; ++y) xv += pp[(size_t)y * NRL];
        }
        if (fb != nullptr) xv += fb[col];
        ss[base + col] = xv;
        vv[c] = xv;
        s += xv;
        q += xv * xv;
    }
#pragma unroll
    for (int off = 32; off; off >>= 1) {
        s += __shfl_xor(s, off);
        q += __shfl_xor(q, off);
    }
    __shared__ float red[8];
    int wvi = tid >> 6;
    if ((tid & 63) == 0) { red[wvi] = s; red[4 + wvi] = q; }
    __syncthreads();
    s = red[0] + red[1] + red[2] + red[3];
    q = red[4] + red[5] + red[6] + red[7];
    float mean = s * (1.f / 2048.f);
    float var = q * (1.f / 2048.f) - mean * mean;
    float rstd = rsqrtf(var + 1e-5f);
#pragma unroll
    for (int c = 0; c < 8; ++c) {
        int col = tid + c * 256;
        lnout[base + col] = (vv[c] - mean) * rstd * g[col] + b[col];
    }
}

// one block per head; sums the S qkv k-planes inline
__global__ void attn_kernel(const float* __restrict__ Pq, float* __restrict__ imv,
                            int S) {
    int h = blockIdx.x, lane = threadIdx.x;
    const float scale = 0.08838834764831845f;  // 1/sqrt(128)
    float run0 = 0.f, run1 = 0.f;
    for (int i = 0; i < 17; ++i) {
        const size_t idx = (size_t)i * 6144 + h * 128;
        float q0 = 0.f, q1 = 0.f, k0 = 0.f, k1 = 0.f, v0 = 0.f, v1 = 0.f;
        for (int s = 0; s < S; ++s) {
            const float* base = Pq + (size_t)s * 104448 + idx;
            q0 += base[lane];        q1 += base[lane + 64];
            k0 += base[2048 + lane]; k1 += base[2048 + lane + 64];
            v0 += base[4096 + lane]; v1 += base[4096 + lane + 64];
        }
        float p = q0 * k0 + q1 * k1;
#pragma unroll
        for (int off = 32; off; off >>= 1) p += __shfl_xor(p, off);
        float rsa = p * scale;
        float iv0 = rsa * v0, iv1 = rsa * v1;
        float o0, o1;
        if (i < 16) { run0 += iv0; run1 += iv1; o0 = run0; o1 = run1; }
        else        { o0 = iv0; o1 = iv1; }
        imv[(size_t)i * 2048 + h * 128 + lane] = o0;
        imv[(size_t)i * 2048 + h * 128 + lane + 64] = o1;
    }
}

extern "C" void kernel_launch(void* const* d_in, const int* in_sizes, int n_in,
                              void* d_out, int out_size, void* d_ws, size_t ws_size,
                              hipStream_t stream) {
    const float* x      = (const float*)d_in[0];
    const float* weight = (const float*)d_in[1];
    const float* bias   = (const float*)d_in[2];
    const float* cls    = (const float*)d_in[3];
    const float* Wqkv   = (const float*)d_in[4];
    const float* Wo     = (const float*)d_in[5];
    const float* ln1_g  = (const float*)d_in[6];
    const float* ln1_b  = (const float*)d_in[7];
    const float* ln2_g  = (const float*)d_in[8];
    const float* ln2_b  = (const float*)d_in[9];
    const float* ln3_g  = (const float*)d_in[10];
    const float* ln3_b  = (const float*)d_in[11];
    const float* fc1_w  = (const float*)d_in[12];
    const float* fc1_b  = (const float*)d_in[13];
    const float* fc2_w  = (const float*)d_in[14];
    const float* fc2_b  = (const float*)d_in[15];
    float* out = (float*)d_out;

    float* ws     = (float*)d_ws;
    float* ss     = ws;                  // 34816
    float* altx   = ws + 34816;          // 32768
    float* imv    = ws + 67584;          // 34816
    float* tbuf   = ws + 102400;         // 139264
    float* ln1buf = ws + 241664;         // 34816
    float* ln2buf = ws + 276480;         // 34816
    float* P      = ws + 311296;         // 417792 max

    k0_init<<<136, 256, 0, stream>>>(x, bias, cls, ss, altx);
    // ss[1:17] += altx @ weight.T  (ksplit 4, NC=2 -> slab 512)
    gemmP<16, 2><<<dim3(128, 4), 256, 0, stream>>>(weight, altx, P, 2048, 2048);
    redln<<<17, 256, 0, stream>>>(P, 4, 1, 32768, nullptr, ss, ln1_g, ln1_b, ln1buf);

    for (int k = 0; k < 4; ++k) {
        // qkv = Wqkv[k] @ ln1buf  (ksplit 2, NC=4 -> slab 1024)
        gemmP<17, 4><<<dim3(384, 2), 256, 0, stream>>>(
            Wqkv + (size_t)k * 12582912, ln1buf, P, 6144, 2048);
        attn_kernel<<<16, 64, 0, stream>>>(P, imv, 2);
        // ss += imv @ Wo[k].T  (ksplit 4, NC=2 -> slab 512)
        gemmP<17, 2><<<dim3(128, 4), 256, 0, stream>>>(
            Wo + (size_t)k * 4194304, imv, P, 2048, 2048);
        redln<<<17, 256, 0, stream>>>(P, 4, 0, 34816, nullptr, ss, ln2_g, ln2_b, ln2buf);
        // fc1 raw  (ksplit 2, NC=4 -> slab 1024)
        gemmP<17, 4><<<dim3(512, 2), 256, 0, stream>>>(fc1_w, ln2buf, P, 8192, 2048);
        red_gelu<<<544, 256, 0, stream>>>(P, fc1_b, tbuf, 2, 139264);
        // fc2  (ksplit 8, NC=4 -> slab 1024)
        gemmP<17, 4><<<dim3(128, 8), 256, 0, stream>>>(fc2_w, tbuf, P, 2048, 8192);
        if (k < 3)
            redln<<<17, 256, 0, stream>>>(P, 8, 0, 34816, fc2_b, ss, ln1_g, ln1_b, ln1buf);
        else
            redln<<<17, 256, 0, stream>>>(P, 8, 0, 34816, fc2_b, ss, ln3_g, ln3_b, out);
    }
}